// Round 5
// baseline (1226.969 us; speedup 1.0000x reference)
//
#include <hip/hip_runtime.h>

// UNetDecoderBlock: sparse 2x upsample + hash skip-add + 3x submanifold 3^3
// conv (64->64, BN batch-stats + LeakyReLU) + residual.
// NX=40000, M=320000, S_out=128.
//
// Round 5:
//  - upsample rewritten as bf16 MFMA GEMM (x pre-converted to bf16, all 8
//    octant weights packed into one B-frag buffer), skip-add + table_o
//    scatter fused in the epilogue.
//  - conv: 32 rows/wave, explicit 4-phase unrolled k-loop with 4 A-buffers
//    (gather issued 2 phases ahead) and 2 B-buffers (1 phase ahead); phase 27
//    is a zero-A guard so the 28-phase loop needs no tail.

#define S2 128
#define TABN (S2 * S2 * S2)

typedef __attribute__((ext_vector_type(8))) short short8;
typedef __attribute__((ext_vector_type(4))) float f32x4;

__device__ inline float b2f(unsigned short u) {
    return __uint_as_float(((unsigned)u) << 16);
}
__device__ inline unsigned short f2b(float f) {   // RNE
    unsigned u = __float_as_uint(f);
    return (unsigned short)((u + 0x7FFF + ((u >> 16) & 1)) >> 16);
}

// ---------------- fp32 -> bf16 row-major convert (x_feats) ----------------
__global__ void k_cvt(const float* __restrict__ x, unsigned short* __restrict__ xb, int n8) {
    int t = blockIdx.x * 256 + threadIdx.x;
    if (t >= n8) return;
    float4 a = ((const float4*)x)[t * 2];
    float4 b = ((const float4*)x)[t * 2 + 1];
    short8 r;
    r[0] = (short)f2b(a.x); r[1] = (short)f2b(a.y); r[2] = (short)f2b(a.z); r[3] = (short)f2b(a.w);
    r[4] = (short)f2b(b.x); r[5] = (short)f2b(b.y); r[6] = (short)f2b(b.z); r[7] = (short)f2b(b.w);
    ((short8*)xb)[t] = r;
}

// ---------------- skip-coord hash scatter ----------------
__global__ void k_scatter_skip(const int* __restrict__ sc, int* __restrict__ table_s, int NS) {
    int i = blockIdx.x * 256 + threadIdx.x;
    if (i >= NS) return;
    table_s[(sc[i * 3] * S2 + sc[i * 3 + 1]) * S2 + sc[i * 3 + 2]] = i;
}

// ---------------- conv weight pack: fp32 [27][64][64] -> bf16 B-frag order --
// wpk[k*4096 + ks*2048 + nt*512 + lane*8 + j] =
//   W[k][ d = ks*32 + (lane>>4)*8 + j ][ c = nt*16 + (lane&15) ]
__global__ void k_packw(const float* __restrict__ w, unsigned short* __restrict__ wpk) {
    int t = blockIdx.x * 256 + threadIdx.x;
    if (t >= 27 * 4096) return;
    int j = t & 7, l = (t >> 3) & 63, nt = (t >> 9) & 3, ks = (t >> 11) & 1, k = t >> 12;
    int d = ks * 32 + (l >> 4) * 8 + j;
    int c = nt * 16 + (l & 15);
    wpk[t] = f2b(w[(k * 64 + d) * 64 + c]);
}

// ---------------- upsample weight pack: w_up fp32 [8][128][64] -> B-frag ----
// Wcat[d][col], col = o*64+c, value = w_up[7-o][d][c]
// wpku[(ks*32 + nt)*512 + lane*8 + j], d = ks*32+(lane>>4)*8+j, col = nt*16+(lane&15)
__global__ void k_packwup(const float* __restrict__ w, unsigned short* __restrict__ wpku) {
    int t = blockIdx.x * 256 + threadIdx.x;
    if (t >= 65536) return;
    int j = t & 7, l = (t >> 3) & 63, nt = (t >> 9) & 31, ks = t >> 14;
    int d = ks * 32 + (l >> 4) * 8 + j;
    int col = nt * 16 + (l & 15);
    int o = col >> 6, c = col & 63;
    wpku[t] = f2b(w[(size_t)(7 - o) * 8192 + d * 64 + c]);
}

// ---------------- upsample MFMA + skip-add + table_o scatter ----------------
// block: 16 parents, 256 threads = 4 waves; wave w -> cols [w*128, w*128+128)
// (= octants o = 2w, 2w+1). K=128 in 4 chunks of 32.
__global__ __launch_bounds__(256) void k_upsample_mfma(
    const unsigned short* __restrict__ xb, const unsigned short* __restrict__ wpku,
    const int* __restrict__ cords, const float* __restrict__ skipf,
    const int* __restrict__ table_s, int* __restrict__ table_o,
    unsigned short* __restrict__ feats, int NX) {
    int tid = threadIdx.x;
    int lane = tid & 63, w = tid >> 6;
    int l15 = lane & 15, kg = lane >> 4;
    int p0 = blockIdx.x * 16;

    f32x4 acc[8];
#pragma unroll
    for (int nt = 0; nt < 8; ++nt) acc[nt] = (f32x4){0.f, 0.f, 0.f, 0.f};

#pragma unroll
    for (int ks = 0; ks < 4; ++ks) {
        short8 a = *(const short8*)(xb + (size_t)(p0 + l15) * 128 + ks * 32 + kg * 8);
        const unsigned short* wb = wpku + ((size_t)(ks * 32 + w * 8) * 64 + lane) * 8;
#pragma unroll
        for (int nt = 0; nt < 8; ++nt) {
            short8 b = *(const short8*)(wb + nt * 512);
            acc[nt] = __builtin_amdgcn_mfma_f32_16x16x32_bf16(a, b, acc[nt], 0, 0, 0);
        }
    }

    // epilogue: skip-add + bf16 store + table_o scatter
#pragma unroll
    for (int j = 0; j < 4; ++j) {
        int parent = p0 + kg * 4 + j;
        int cx = cords[parent * 3], cy = cords[parent * 3 + 1], cz = cords[parent * 3 + 2];
#pragma unroll
        for (int nt = 0; nt < 8; ++nt) {
            int o = w * 2 + (nt >> 2);
            int c = (nt & 3) * 16 + l15;
            int X = 2 * cx + (o >> 2), Y = 2 * cy + ((o >> 1) & 1), Z = 2 * cz + (o & 1);
            int lin = (X * S2 + Y) * S2 + Z;
            int row = parent * 8 + o;
            int js = table_s[lin];
            float v = acc[nt][j];
            if (js >= 0) v += skipf[(size_t)js * 64 + c];
            feats[(size_t)row * 64 + c] = f2b(v);
            if (c == 0) table_o[lin] = row;
        }
    }
}

// ---------------- neighbor table (27 x M); invalid -> M (guard row) --------
__global__ void k_build_nbr(const int* __restrict__ cords, const int* __restrict__ table_o,
                            int* __restrict__ nbr, int M) {
    int m = blockIdx.x * 256 + threadIdx.x;
    if (m >= M) return;
    int n = m >> 3, o = m & 7;
    int X = 2 * cords[n * 3] + (o >> 2);
    int Y = 2 * cords[n * 3 + 1] + ((o >> 1) & 1);
    int Z = 2 * cords[n * 3 + 2] + (o & 1);
#pragma unroll
    for (int kk = 0; kk < 27; ++kk) {
        int nx = X + kk / 9 - 1, ny = Y + (kk / 3) % 3 - 1, nz = Z + kk % 3 - 1;
        int idx = -1;
        if ((unsigned)nx < (unsigned)S2 && (unsigned)ny < (unsigned)S2 && (unsigned)nz < (unsigned)S2)
            idx = table_o[(nx * S2 + ny) * S2 + nz];
        nbr[(size_t)kk * M + m] = (idx < 0) ? M : idx;   // guard row on invalid
    }
}

// ---------------- MFMA gather-conv, 4-phase pipelined ----------------
// block: 256 threads = 4 waves; wave owns 32 rows x 64 cols (acc[2][4]).
// A gathered 2 phases ahead (4 buffers), B 1 phase ahead (2 buffers).
__global__ __launch_bounds__(256, 2) void k_conv_mfma(
    const unsigned short* __restrict__ fin, const unsigned short* __restrict__ wpk,
    const int* __restrict__ nbr, unsigned short* __restrict__ zout,
    float* __restrict__ stats, int M) {
    __shared__ int idx_lds[32 * 128];
    int tid = threadIdx.x;
    int lane = tid & 63, wv = tid >> 6;
    int l15 = lane & 15, kg = lane >> 4;
    int rblk = blockIdx.x * 128;
    int rw = wv * 32;

    {   // stage 27x128 neighbor indices; rows 27..31 = guard (M)
        int col = (tid & 31) * 4;
        int q0 = tid >> 5;
        for (int q = q0; q < 27; q += 8) {
            int4 v = *(const int4*)(nbr + (size_t)q * M + rblk + col);
            *(int4*)&idx_lds[q * 128 + col] = v;
        }
        for (int i = tid; i < 5 * 128; i += 256) idx_lds[27 * 128 + i] = M;
    }
    __syncthreads();

    f32x4 acc[2][4];
#pragma unroll
    for (int m = 0; m < 2; ++m)
#pragma unroll
        for (int nt = 0; nt < 4; ++nt) acc[m][nt] = (f32x4){0.f, 0.f, 0.f, 0.f};

    short8 A0[2][2], A1[2][2], A2[2][2], A3[2][2], B0[2][4], B1[2][4];

#define LOADA(Ab, kk)                                                          \
    {                                                                          \
        _Pragma("unroll")                                                      \
        for (int m = 0; m < 2; ++m) {                                          \
            int idx = idx_lds[(kk) * 128 + rw + m * 16 + l15];                 \
            const unsigned short* p = fin + (size_t)idx * 64 + kg * 8;         \
            Ab[m][0] = *(const short8*)p;                                      \
            Ab[m][1] = *(const short8*)(p + 32);                               \
        }                                                                      \
    }
#define LOADB(Bb, kk)                                                          \
    {                                                                          \
        int kb = (kk) > 26 ? 26 : (kk);                                        \
        const unsigned short* wb = wpk + (size_t)kb * 4096 + lane * 8;         \
        _Pragma("unroll")                                                      \
        for (int ks = 0; ks < 2; ++ks)                                         \
            _Pragma("unroll")                                                  \
            for (int nt = 0; nt < 4; ++nt)                                     \
                Bb[ks][nt] = *(const short8*)(wb + ks * 2048 + nt * 512);      \
    }
#define MFMAQ(Ab, Bb)                                                          \
    {                                                                          \
        _Pragma("unroll")                                                      \
        for (int m = 0; m < 2; ++m)                                            \
            _Pragma("unroll")                                                  \
            for (int nt = 0; nt < 4; ++nt) {                                   \
                acc[m][nt] = __builtin_amdgcn_mfma_f32_16x16x32_bf16(          \
                    Ab[m][0], Bb[0][nt], acc[m][nt], 0, 0, 0);                 \
                acc[m][nt] = __builtin_amdgcn_mfma_f32_16x16x32_bf16(          \
                    Ab[m][1], Bb[1][nt], acc[m][nt], 0, 0, 0);                 \
            }                                                                  \
    }

    LOADA(A0, 0); LOADA(A1, 1); LOADB(B0, 0);
    for (int k = 0; k < 28; k += 4) {   // phases k..k+3; phase 27 has A==0
        LOADA(A2, k + 2); LOADB(B1, k + 1); MFMAQ(A0, B0);
        LOADA(A3, k + 3); LOADB(B0, k + 2); MFMAQ(A1, B1);
        LOADA(A0, k + 4); LOADB(B1, k + 3); MFMAQ(A2, B0);
        LOADA(A1, k + 5); LOADB(B0, k + 4); MFMAQ(A3, B1);
    }
#undef LOADA
#undef LOADB
#undef MFMAQ

    // epilogue: bf16 store + BN batch-stats
    float s[4] = {0.f, 0.f, 0.f, 0.f}, q[4] = {0.f, 0.f, 0.f, 0.f};
#pragma unroll
    for (int m = 0; m < 2; ++m)
#pragma unroll
        for (int nt = 0; nt < 4; ++nt)
#pragma unroll
            for (int j = 0; j < 4; ++j) {
                float v = acc[m][nt][j];
                int row = rblk + rw + m * 16 + kg * 4 + j;
                zout[(size_t)row * 64 + nt * 16 + l15] = f2b(v);
                s[nt] += v; q[nt] += v * v;
            }
#pragma unroll
    for (int nt = 0; nt < 4; ++nt) {
        float ss = s[nt], qq = q[nt];
        ss += __shfl_xor(ss, 16); ss += __shfl_xor(ss, 32);
        qq += __shfl_xor(qq, 16); qq += __shfl_xor(qq, 32);
        if (kg == 0) {
            atomicAdd(&stats[nt * 16 + l15], ss);
            atomicAdd(&stats[64 + nt * 16 + l15], qq);
        }
    }
}

// ---------------- BN coefficient finalize ----------------
__global__ void k_finalize(const float* __restrict__ stats, const float* __restrict__ g,
                           const float* __restrict__ b, float* __restrict__ coef, float invM) {
    int c = threadIdx.x;
    if (c >= 64) return;
    float mu = stats[c] * invM;
    float var = stats[64 + c] * invM - mu * mu;
    float sc = g[c] * rsqrtf(var + 1e-4f);
    coef[c] = sc;
    coef[64 + c] = b[c] - mu * sc;
}

// ---------------- elementwise BN+lrelu(0.05), in place, bf16 ----------------
__global__ void k_xform(unsigned short* __restrict__ z, const float* __restrict__ coef, int n8) {
    int t = blockIdx.x * 256 + threadIdx.x;
    if (t >= n8) return;
    short8 v = ((const short8*)z)[t];
    int cb = (t * 8) & 63;
    short8 r;
#pragma unroll
    for (int j = 0; j < 8; ++j) {
        float f = b2f((unsigned short)v[j]) * coef[cb + j] + coef[64 + cb + j];
        f = fmaxf(f, 0.05f * f);
        r[j] = (short)f2b(f);
    }
    ((short8*)z)[t] = r;
}

// ---------------- residual epilogue: lrelu(bn3(z3) + x1, 0.333) -> fp32 -----
__global__ void k_final(const unsigned short* __restrict__ z3,
                        const unsigned short* __restrict__ x1,
                        const float* __restrict__ coef3, float* __restrict__ out, int n8) {
    int t = blockIdx.x * 256 + threadIdx.x;
    if (t >= n8) return;
    short8 v3 = ((const short8*)z3)[t];
    short8 v1 = ((const short8*)x1)[t];
    int cb = (t * 8) & 63;
    float rr[8];
#pragma unroll
    for (int j = 0; j < 8; ++j) {
        float f3 = b2f((unsigned short)v3[j]) * coef3[cb + j] + coef3[64 + cb + j];
        float r = f3 + b2f((unsigned short)v1[j]);
        rr[j] = fmaxf(r, 0.333f * r);
    }
    ((float4*)out)[t * 2] = make_float4(rr[0], rr[1], rr[2], rr[3]);
    ((float4*)out)[t * 2 + 1] = make_float4(rr[4], rr[5], rr[6], rr[7]);
}

extern "C" void kernel_launch(void* const* d_in, const int* in_sizes, int n_in,
                              void* d_out, int out_size, void* d_ws, size_t ws_size,
                              hipStream_t stream) {
    const float* x_feats    = (const float*)d_in[0];
    const float* skip_feats = (const float*)d_in[1];
    const float* w_up       = (const float*)d_in[2];
    const float* w1         = (const float*)d_in[3];
    const float* w2         = (const float*)d_in[4];
    const float* w3         = (const float*)d_in[5];
    const float* g1 = (const float*)d_in[6],  *b1 = (const float*)d_in[7];
    const float* g2 = (const float*)d_in[8],  *b2 = (const float*)d_in[9];
    const float* g3 = (const float*)d_in[10], *b3 = (const float*)d_in[11];
    const int* cords      = (const int*)d_in[12];
    const int* skip_cords = (const int*)d_in[13];
    int NX = in_sizes[12] / 3;
    int NS = in_sizes[13] / 3;
    int M = NX * 8;

    char* ws = (char*)d_ws;
    size_t off = 0;
    auto alloc = [&](size_t bytes) -> char* {
        char* p = ws + off;
        off += (bytes + 255) & ~(size_t)255;
        return p;
    };
    int* table_s = (int*)alloc((size_t)TABN * 4);
    int* table_o = (int*)alloc((size_t)TABN * 4);
    int* nbr     = (int*)alloc((size_t)27 * M * 4);
    unsigned short* A = (unsigned short*)alloc((size_t)(M + 1) * 64 * 2);  // feats -> z3
    unsigned short* B = (unsigned short*)alloc((size_t)(M + 1) * 64 * 2);  // z1 -> x1
    unsigned short* C = (unsigned short*)alloc((size_t)(M + 1) * 64 * 2);  // z2 -> x2
    unsigned short* xb   = (unsigned short*)alloc((size_t)NX * 128 * 2);
    unsigned short* wpku = (unsigned short*)alloc(65536 * 2);
    unsigned short* wp1 = (unsigned short*)alloc(27 * 4096 * 2);
    unsigned short* wp2 = (unsigned short*)alloc(27 * 4096 * 2);
    unsigned short* wp3 = (unsigned short*)alloc(27 * 4096 * 2);
    float* stats = (float*)alloc(384 * 4);
    float* coefs = (float*)alloc(384 * 4);

    hipMemsetAsync(table_s, 0xFF, (size_t)TABN * 4, stream);
    hipMemsetAsync(table_o, 0xFF, (size_t)TABN * 4, stream);
    hipMemsetAsync(stats, 0, 384 * 4, stream);
    // zero guard rows (row M) of all activation buffers
    hipMemsetAsync(A + (size_t)M * 64, 0, 128, stream);
    hipMemsetAsync(B + (size_t)M * 64, 0, 128, stream);
    hipMemsetAsync(C + (size_t)M * 64, 0, 128, stream);

    float invM = 1.f / (float)M;
    int n8 = M * 64 / 8;

    k_cvt<<<(NX * 16 + 255) / 256, 256, 0, stream>>>(x_feats, xb, NX * 16);
    k_scatter_skip<<<(NS + 255) / 256, 256, 0, stream>>>(skip_cords, table_s, NS);
    k_packwup<<<256, 256, 0, stream>>>(w_up, wpku);
    k_packw<<<432, 256, 0, stream>>>(w1, wp1);
    k_packw<<<432, 256, 0, stream>>>(w2, wp2);
    k_packw<<<432, 256, 0, stream>>>(w3, wp3);
    k_upsample_mfma<<<NX / 16, 256, 0, stream>>>(xb, wpku, cords, skip_feats,
                                                 table_s, table_o, A, NX);
    k_build_nbr<<<(M + 255) / 256, 256, 0, stream>>>(cords, table_o, nbr, M);

    k_conv_mfma<<<M / 128, 256, 0, stream>>>(A, wp1, nbr, B, stats, M);
    k_finalize<<<1, 64, 0, stream>>>(stats, g1, b1, coefs, invM);
    k_xform<<<(n8 + 255) / 256, 256, 0, stream>>>(B, coefs, n8);          // B := x1

    k_conv_mfma<<<M / 128, 256, 0, stream>>>(B, wp2, nbr, C, stats + 128, M);
    k_finalize<<<1, 64, 0, stream>>>(stats + 128, g2, b2, coefs + 128, invM);
    k_xform<<<(n8 + 255) / 256, 256, 0, stream>>>(C, coefs + 128, n8);    // C := x2

    k_conv_mfma<<<M / 128, 256, 0, stream>>>(C, wp3, nbr, A, stats + 256, M);
    k_finalize<<<1, 64, 0, stream>>>(stats + 256, g3, b3, coefs + 256, invM);

    k_final<<<(n8 + 255) / 256, 256, 0, stream>>>(A, B, coefs + 256, (float*)d_out, n8);
}